// Round 4
// baseline (1542.460 us; speedup 1.0000x reference)
//
#include <hip/hip_runtime.h>
#include <math.h>

#define NB 16
#define NSQ 512
#define NMAT (NB*NSQ)   // 8192
#define NF 1024         // 32*32
#define NSWEEP 7        // 6 sweeps FAILS (absmax 0.195); 7 hits the comparison floor.
#define SB 36           // LDS row stride (floats): 144B = multiple of 16 -> b128-aligned rows

// ---------------------------------------------------------------------------
// Packed-f32 helpers (VOP3P, gfx90a+/gfx950). op_sel broadcasts the scalar
// coefficient from a (c,s) register pair - no splat moves needed.
//   pk_mul_blo(a,b)      = a * (b.lo, b.lo)
//   pk_mul_bhi(a,b)      = a * (b.hi, b.hi)
//   pk_fma_blo(a,b,c)    = a * (b.lo, b.lo) + c
//   pk_fma_bhi(a,b,c)    = a * (b.hi, b.hi) + c
//   pk_fma_bhi_neg(a,b,c)= -(a * (b.hi, b.hi)) + c
// ---------------------------------------------------------------------------
typedef float f32x2 __attribute__((ext_vector_type(2)));

__device__ __forceinline__ f32x2 pk_mul_blo(f32x2 a, f32x2 b) {
  f32x2 d;
  asm("v_pk_mul_f32 %0, %1, %2 op_sel:[0,0] op_sel_hi:[1,0]"
      : "=v"(d) : "v"(a), "v"(b));
  return d;
}
__device__ __forceinline__ f32x2 pk_mul_bhi(f32x2 a, f32x2 b) {
  f32x2 d;
  asm("v_pk_mul_f32 %0, %1, %2 op_sel:[0,1] op_sel_hi:[1,1]"
      : "=v"(d) : "v"(a), "v"(b));
  return d;
}
__device__ __forceinline__ f32x2 pk_fma_blo(f32x2 a, f32x2 b, f32x2 c) {
  f32x2 d;
  asm("v_pk_fma_f32 %0, %1, %2, %3 op_sel:[0,0,0] op_sel_hi:[1,0,1]"
      : "=v"(d) : "v"(a), "v"(b), "v"(c));
  return d;
}
__device__ __forceinline__ f32x2 pk_fma_bhi(f32x2 a, f32x2 b, f32x2 c) {
  f32x2 d;
  asm("v_pk_fma_f32 %0, %1, %2, %3 op_sel:[0,1,0] op_sel_hi:[1,1,1]"
      : "=v"(d) : "v"(a), "v"(b), "v"(c));
  return d;
}
__device__ __forceinline__ f32x2 pk_fma_bhi_neg(f32x2 a, f32x2 b, f32x2 c) {
  f32x2 d;
  asm("v_pk_fma_f32 %0, %1, %2, %3 op_sel:[0,1,0] op_sel_hi:[1,1,1] neg_lo:[1,0,0] neg_hi:[1,0,0]"
      : "=v"(d) : "v"(a), "v"(b), "v"(c));
  return d;
}

// ---------------------------------------------------------------------------
// Kernel A: Cayley maps. C = (I - X)(I + X)^{-1}, X = W - W^T.
// ---------------------------------------------------------------------------
__global__ __launch_bounds__(64) void cayley_kernel(
    const float* __restrict__ qw, const float* __restrict__ kw,
    const float* __restrict__ vw, float* __restrict__ Cout) {
  __shared__ float M[32][33];
  __shared__ float R[32][33];
  __shared__ float fac[32];
  const float* W = (blockIdx.x == 0) ? qw : ((blockIdx.x == 1) ? kw : vw);
  const int t = threadIdx.x;
  for (int idx = t; idx < 1024; idx += 64) {
    int i = idx >> 5, j = idx & 31;
    float xv = W[i*32+j] - W[j*32+i];
    float d = (i == j) ? 1.0f : 0.0f;
    M[i][j] = d - xv;
    R[i][j] = d + xv;
  }
  __syncthreads();
  for (int k = 0; k < 32; ++k) {
    float inv = 1.0f / M[k][k];
    __syncthreads();
    if (t < 32) M[k][t] *= inv; else R[k][t-32] *= inv;
    __syncthreads();
    if (t < 32) fac[t] = M[t][k];
    __syncthreads();
    if (t < 32) {
      float mk = M[k][t];
      for (int i = 0; i < 32; ++i) {
        if (i == k) continue;
        M[i][t] -= fac[i] * mk;
      }
    } else {
      int tc = t - 32;
      float rk = R[k][tc];
      for (int i = 0; i < 32; ++i) {
        if (i == k) continue;
        R[i][tc] -= fac[i] * rk;
      }
    }
    __syncthreads();
  }
  // R = C^T ; store C row-major: C[p][q] = R[q][p]
  for (int idx = t; idx < 1024; idx += 64) {
    int p = idx >> 5, q = idx & 31;
    Cout[blockIdx.x * 1024 + idx] = R[q][p];
  }
}

// ---------------------------------------------------------------------------
// Kernel B: per-matrix sym eigendecomposition (parallel Jacobi, XOR pairing),
// then S = V log(w) V^T (zero diag), then q/k/v = offdiag(C S C^T) + norms.
// R16: EXACT R10 structure (3 LDS buffers, 128 thr, register index math,
// LDS-staged C epilogue) + packed-f32 (v_pk_fma_f32) rotation compute:
// Vt phase & r==1 phase A 16->8 VALU; 2x2 phase 16->8 VALU per u-block.
// op_sel broadcasts (c,s) from the pair - no splat moves.
// [R13 LESSON: 1-wave/64-thr LOSES - VGPR 116 halves resident waves.]
// [R14 LESSON: LDS pair-offset tables LOSE - conflicts 1.3e8->4.4e8, +515us.
//  Never add sweep-loop LDS traffic; index VALU is cheap.]
// [R15 LESSON: global-C epilogue LOSES - VGPR 52->84, +140us. Keep buf2;
//  occupancy was never LDS-capacity-bound.]
// [R8/R9: 2-buffer LDS epilogues cost registers and LOSE.]
// [R4/R5/R6: fused/two-phase r<=3 variants FAILED - do not revisit.]
// ---------------------------------------------------------------------------
__global__ __launch_bounds__(128) void logm_qkv_kernel(
    const float* __restrict__ x, const float* __restrict__ Cm,
    float* __restrict__ qo, float* __restrict__ ko, float* __restrict__ vo,
    float* __restrict__ q2, float* __restrict__ k2) {
  __shared__ __align__(16) float buf0[32*SB];   // A -> Vrow -> (per w) C
  __shared__ __align__(16) float buf1[32*SB];   // Vt -> T (=offdiag S)
  __shared__ __align__(16) float buf2[32*SB];   // U
  __shared__ __align__(16) float2 cs[16];
  __shared__ __align__(16) float lw[32];
  __shared__ float wsum[2];
  const int t = threadIdx.x;
  const int m = blockIdx.x;
  const float* xm = x + (size_t)m * NF;

  // init A = x (stride SB, b128) and Vt = I : 256 float4 tasks, 2/thread
  #pragma unroll
  for (int s = 0; s < 2; ++s) {
    int fi = t + 128*s;              // float4 index 0..255
    int i = fi >> 3, j4 = (fi & 7) << 2;
    float4 xv = *(const float4*)&xm[(size_t)fi*4];
    *(float4*)&buf0[i*SB + j4] = xv;
    float4 iv;
    iv.x = (i == j4+0) ? 1.0f : 0.0f;
    iv.y = (i == j4+1) ? 1.0f : 0.0f;
    iv.z = (i == j4+2) ? 1.0f : 0.0f;
    iv.w = (i == j4+3) ? 1.0f : 0.0f;
    *(float4*)&buf1[i*SB + j4] = iv;
  }
  __syncthreads();

  const int abase = t >> 4;    // row-pair group 0..7
  const int bI = t & 15;       // col-pair index
  const int pi = abase & 1;    // role-swap parity

  for (int sw = 0; sw < NSWEEP; ++sw) {
    for (int r = 1; r < 32; ++r) {
      const int h = 31 - __builtin_clz((unsigned)r);
      const int lowmask = (1 << h) - 1;
      // phase 1: rotation angles for the 16 disjoint pairs {p, p^r}
      if (t < 16) {
        int p = ((t >> h) << (h+1)) | (t & lowmask);
        int q = p ^ r;
        float apq = buf0[p*SB+q];
        float c = 1.0f, s = 0.0f;
        if (fabsf(apq) > 1e-36f) {
          float app = buf0[p*SB+p];
          float aqq = buf0[q*SB+q];
          float tau = (aqq - app) / (2.0f * apq);
          float tt = 1.0f / (fabsf(tau) + sqrtf(1.0f + tau*tau));
          tt = (tau < 0.0f) ? -tt : tt;
          c = 1.0f / sqrtf(1.0f + tt*tt);
          s = tt * c;
        }
        cs[t] = make_float2(c, s);
      }
      __syncthreads();
      if (r == 1) {
        // --- phase A: row rotations B = J^T A (b128, packed); pairs
        //     (2k,2k+1); 128 tasks (16 pairs x 8 chunks), 1 per thread ---
        {
          int pr = t >> 3;                 // pair 0..15
          int ch = (t & 7) << 2;           // column chunk
          int p = pr << 1;                 // h=0 -> p = 2*pr
          int q = p | 1;
          f32x2 C2 = *(f32x2*)&cs[pr];     // (c,s)
          float4 ap = *(float4*)&buf0[p*SB + ch];
          float4 aq = *(float4*)&buf0[q*SB + ch];
          f32x2 ap01; ap01.x = ap.x; ap01.y = ap.y;
          f32x2 ap23; ap23.x = ap.z; ap23.y = ap.w;
          f32x2 aq01; aq01.x = aq.x; aq01.y = aq.y;
          f32x2 aq23; aq23.x = aq.z; aq23.y = aq.w;
          f32x2 np01 = pk_fma_bhi_neg(aq01, C2, pk_mul_blo(ap01, C2)); // c*ap - s*aq
          f32x2 np23 = pk_fma_bhi_neg(aq23, C2, pk_mul_blo(ap23, C2));
          f32x2 nq01 = pk_fma_bhi(ap01, C2, pk_mul_blo(aq01, C2));     // s*ap + c*aq
          f32x2 nq23 = pk_fma_bhi(ap23, C2, pk_mul_blo(aq23, C2));
          float4 np, nq;
          np.x = np01.x; np.y = np01.y; np.z = np23.x; np.w = np23.y;
          nq.x = nq01.x; nq.y = nq01.y; nq.z = nq23.x; nq.w = nq23.y;
          *(float4*)&buf0[p*SB + ch] = np;
          *(float4*)&buf0[q*SB + ch] = nq;
        }
        __syncthreads();   // r is loop-uniform -> all threads reach this
        // --- phase B: col rotations A' = B J, in-register per row-chunk;
        //     local col pairs (0,1) w/ cs[2c] and (2,3) w/ cs[2c+1];
        //     256 tasks, 2 per thread ---
        #pragma unroll
        for (int s4 = 0; s4 < 2; ++s4) {
          int tsk = t + 128*s4;            // 0..255
          int i = tsk >> 3;                // row 0..31
          int cch = tsk & 7;               // chunk 0..7 (cols 4c..4c+3)
          float2 cA = cs[2*cch];
          float2 cB = cs[2*cch+1];
          float4 y = *(float4*)&buf0[i*SB + 4*cch];
          float4 z;
          z.x = cA.x*y.x - cA.y*y.y;  z.y = fmaf(cA.y, y.x, cA.x*y.y);
          z.z = cB.x*y.z - cB.y*y.w;  z.w = fmaf(cB.y, y.z, cB.x*y.w);
          *(float4*)&buf0[i*SB + 4*cch] = z;
        }
      } else {
        // blocked 2x2 update, pi-swapped, packed-f32; 256 blocks, 2/thread.
        int pb = ((bI >> h) << (h+1)) | (bI & lowmask);
        int qb = pb ^ r;
        if (pi) { int tmp = pb; pb = qb; qb = tmp; }
        const float2 cb2 = cs[bI];
        const float cbb = cb2.x;
        const float sbb = pi ? -cb2.y : cb2.y;
        f32x2 CB;  CB.x  = cbb;  CB.y  = sbb;   // (cbb, sbb)
        f32x2 CBn; CBn.x = -sbb; CBn.y = cbb;   // (-sbb, cbb)
        #pragma unroll
        for (int u = 0; u < 2; ++u) {
          int a = abase + 8*u;
          int pa = ((a >> h) << (h+1)) | (a & lowmask);
          int qa = pa ^ r;
          if (pi) { int tmp = pa; pa = qa; qa = tmp; }
          float2 ca2 = cs[a];
          f32x2 CA; CA.x = ca2.x; CA.y = pi ? -ca2.y : ca2.y;  // (caa, saa)
          float* rp = buf0 + pa*SB;
          float* rq = buf0 + qa*SB;
          f32x2 X1; X1.x = rp[pb]; X1.y = rp[qb];   // (x11, x12)
          f32x2 X2; X2.x = rq[pb]; X2.y = rq[qb];   // (x21, x22)
          // row rotation: Y1 = caa*X1 - saa*X2 ; Y2 = saa*X1 + caa*X2
          f32x2 Y1 = pk_fma_bhi_neg(X2, CA, pk_mul_blo(X1, CA));
          f32x2 Y2 = pk_fma_blo(X2, CA, pk_mul_bhi(X1, CA));
          // col rotation: out = CB*bcast(y_1) + CBn*bcast(y_2)
          f32x2 OP = pk_fma_bhi(CBn, Y1, pk_mul_blo(CB, Y1));
          f32x2 OQ = pk_fma_bhi(CBn, Y2, pk_mul_blo(CB, Y2));
          rp[pb] = OP.x; rp[qb] = OP.y;
          rq[pb] = OQ.x; rq[qb] = OQ.y;
        }
      }
      // V^T row rotations (Vt = J^T Vt, packed), 128 float4 tasks, 1/thread
      {
        int pr = t >> 3;                 // pair 0..15
        int ch = (t & 7) << 2;           // column chunk
        int p = ((pr >> h) << (h+1)) | (pr & lowmask);
        int q = p ^ r;
        f32x2 C2 = *(f32x2*)&cs[pr];     // (c,s)
        float4 vp = *(float4*)&buf1[p*SB + ch];
        float4 vq = *(float4*)&buf1[q*SB + ch];
        f32x2 vp01; vp01.x = vp.x; vp01.y = vp.y;
        f32x2 vp23; vp23.x = vp.z; vp23.y = vp.w;
        f32x2 vq01; vq01.x = vq.x; vq01.y = vq.y;
        f32x2 vq23; vq23.x = vq.z; vq23.y = vq.w;
        f32x2 np01 = pk_fma_bhi_neg(vq01, C2, pk_mul_blo(vp01, C2));
        f32x2 np23 = pk_fma_bhi_neg(vq23, C2, pk_mul_blo(vp23, C2));
        f32x2 nq01 = pk_fma_bhi(vp01, C2, pk_mul_blo(vq01, C2));
        f32x2 nq23 = pk_fma_bhi(vp23, C2, pk_mul_blo(vq23, C2));
        float4 np, nq;
        np.x = np01.x; np.y = np01.y; np.z = np23.x; np.w = np23.y;
        nq.x = nq01.x; nq.y = nq01.y; nq.z = nq23.x; nq.w = nq23.y;
        *(float4*)&buf1[p*SB + ch] = np;
        *(float4*)&buf1[q*SB + ch] = nq;
      }
      __syncthreads();
    }
  }

  if (t < 32) lw[t] = logf(fmaxf(buf0[t*SB+t], 1e-30f));
  __syncthreads();
  // transpose Vt(buf1) -> Vrow(buf0): 1024 scalars, 8 per thread
  #pragma unroll
  for (int s = 0; s < 8; ++s) {
    int idx = t + 128*s;
    int i = idx >> 5, k = idx & 31;
    buf0[i*SB + k] = buf1[k*SB + i];
  }
  __syncthreads();

  // tile partition: 128 threads own 4x2 output tiles (8 row-groups x 16 col-groups)
  const int rg = t >> 4, cg = t & 15;
  const int i0 = rg*4, j0 = cg*2;
  // T = offdiag(S), S[i][j] = sum_k (Vrow[i][k]*lw[k]) * Vrow[j][k]  -> buf1
  {
    float acc[4][2] = {};
    #pragma unroll
    for (int k4 = 0; k4 < 32; k4 += 4) {
      float4 lv = *(float4*)&lw[k4];
      float4 av[4], bv[2];
      #pragma unroll
      for (int d = 0; d < 4; ++d) {
        float4 a4 = *(float4*)&buf0[(i0+d)*SB + k4];
        av[d].x = a4.x*lv.x; av[d].y = a4.y*lv.y; av[d].z = a4.z*lv.z; av[d].w = a4.w*lv.w;
      }
      #pragma unroll
      for (int e = 0; e < 2; ++e)
        bv[e] = *(float4*)&buf0[(j0+e)*SB + k4];
      #pragma unroll
      for (int d = 0; d < 4; ++d)
        #pragma unroll
        for (int e = 0; e < 2; ++e) {
          acc[d][e] = fmaf(av[d].x, bv[e].x, acc[d][e]);
          acc[d][e] = fmaf(av[d].y, bv[e].y, acc[d][e]);
          acc[d][e] = fmaf(av[d].z, bv[e].z, acc[d][e]);
          acc[d][e] = fmaf(av[d].w, bv[e].w, acc[d][e]);
        }
    }
    #pragma unroll
    for (int d = 0; d < 4; ++d) {
      #pragma unroll
      for (int e = 0; e < 2; ++e)
        if (i0+d == j0+e) acc[d][e] = 0.0f;
      float2 z; z.x = acc[d][0]; z.y = acc[d][1];
      *(float2*)&buf1[(i0+d)*SB + j0] = z;
    }
  }
  __syncthreads();

  for (int w = 0; w < 3; ++w) {
    const float* Cw = Cm + w*1024;
    // load C -> buf0 (over dead Vrow), 256 float4, 2 per thread
    #pragma unroll
    for (int s = 0; s < 2; ++s) {
      int fi = t + 128*s;
      int i = fi >> 3, c4 = (fi & 7) << 2;
      *(float4*)&buf0[i*SB + c4] = *(const float4*)&Cw[fi*4];
    }
    __syncthreads();
    // U = C * T (T symmetric): U[i][j] = sum_k C[i][k] * T[j][k] -> buf2
    {
      float acc[4][2] = {};
      #pragma unroll
      for (int k4 = 0; k4 < 32; k4 += 4) {
        float4 av[4], bv[2];
        #pragma unroll
        for (int d = 0; d < 4; ++d)
          av[d] = *(float4*)&buf0[(i0+d)*SB + k4];
        #pragma unroll
        for (int e = 0; e < 2; ++e)
          bv[e] = *(float4*)&buf1[(j0+e)*SB + k4];
        #pragma unroll
        for (int d = 0; d < 4; ++d)
          #pragma unroll
          for (int e = 0; e < 2; ++e) {
            acc[d][e] = fmaf(av[d].x, bv[e].x, acc[d][e]);
            acc[d][e] = fmaf(av[d].y, bv[e].y, acc[d][e]);
            acc[d][e] = fmaf(av[d].z, bv[e].z, acc[d][e]);
            acc[d][e] = fmaf(av[d].w, bv[e].w, acc[d][e]);
          }
      }
      #pragma unroll
      for (int d = 0; d < 4; ++d) {
        float2 z; z.x = acc[d][0]; z.y = acc[d][1];
        *(float2*)&buf2[(i0+d)*SB + j0] = z;
      }
    }
    __syncthreads();
    // Z = U * C^T: Z[i][j] = sum_k U[i][k] * C[j][k]; offdiag -> global
    {
      float acc[4][2] = {};
      #pragma unroll
      for (int k4 = 0; k4 < 32; k4 += 4) {
        float4 av[4], bv[2];
        #pragma unroll
        for (int d = 0; d < 4; ++d)
          av[d] = *(float4*)&buf2[(i0+d)*SB + k4];
        #pragma unroll
        for (int e = 0; e < 2; ++e)
          bv[e] = *(float4*)&buf0[(j0+e)*SB + k4];
        #pragma unroll
        for (int d = 0; d < 4; ++d)
          #pragma unroll
          for (int e = 0; e < 2; ++e) {
            acc[d][e] = fmaf(av[d].x, bv[e].x, acc[d][e]);
            acc[d][e] = fmaf(av[d].y, bv[e].y, acc[d][e]);
            acc[d][e] = fmaf(av[d].z, bv[e].z, acc[d][e]);
            acc[d][e] = fmaf(av[d].w, bv[e].w, acc[d][e]);
          }
      }
      float ss = 0.0f;
      float* outp = (w == 0) ? qo : ((w == 1) ? ko : vo);
      #pragma unroll
      for (int d = 0; d < 4; ++d) {
        #pragma unroll
        for (int e = 0; e < 2; ++e) {
          if (i0+d == j0+e) acc[d][e] = 0.0f;
          ss = fmaf(acc[d][e], acc[d][e], ss);
        }
        float2 z; z.x = acc[d][0]; z.y = acc[d][1];
        *(float2*)&outp[(size_t)m*NF + (i0+d)*32 + j0] = z;
      }
      if (w < 2) {
        #pragma unroll
        for (int off = 32; off > 0; off >>= 1)
          ss += __shfl_down(ss, off);
        if ((t & 63) == 0) wsum[t >> 6] = ss;
      }
      __syncthreads();   // wsum visible; Z reads of buf0/buf2 done
      if (w < 2 && t == 0)
        ((w == 0) ? q2 : k2)[m] = wsum[0] + wsum[1];
    }
  }
}

// ---------------------------------------------------------------------------
// Kernel C1: G[b,j,i] = <kf[b,j], qf[b,i]> (K=1024), fused scores epilogue.
// R12: 128x128 tile, 256 threads, 8x8 micro-tile, K-major (transposed)
// staging -> inner loop is 4 broadcast ds_read_b128 vs 64 fma (compute-bound;
// old 64-tile/4x4 was 16 scalar ds_read per 32 fma -> LDS-bound, ~40% peak).
// Same K-accumulation order per element -> bit-identical output.
// ---------------------------------------------------------------------------
__global__ __launch_bounds__(256) void scores_kernel(
    const float* __restrict__ qf, const float* __restrict__ kf,
    const float* __restrict__ q2, const float* __restrict__ k2,
    float* __restrict__ P) {
  __shared__ float Ks[16][132];   // [k][j] transposed
  __shared__ float Qs[16][132];   // [k][i] transposed
  const int b = blockIdx.z;
  const int j0 = blockIdx.y * 128;
  const int i0 = blockIdx.x * 128;
  const int tx = threadIdx.x & 15, ty = threadIdx.x >> 4;  // i-group, j-group
  const int srow = threadIdx.x >> 1;        // staging row 0..127
  const int sk8  = (threadIdx.x & 1) * 8;   // staging k-offset 0 or 8
  float acc[8][8] = {};
  const float* kb = kf + (size_t)(b*NSQ + j0) * NF;
  const float* qb = qf + (size_t)(b*NSQ + i0) * NF;
  for (int f0 = 0; f0 < NF; f0 += 16) {
    float4 ka = *(const float4*)(kb + (size_t)srow*NF + f0 + sk8);
    float4 kb4 = *(const float4*)(kb + (size_t)srow*NF + f0 + sk8 + 4);
    float4 qa = *(const float4*)(qb + (size_t)srow*NF + f0 + sk8);
    float4 qb4 = *(const float4*)(qb + (size_t)srow*NF + f0 + sk8 + 4);
    __syncthreads();   // prev iteration's reads done before overwrite
    Ks[sk8+0][srow] = ka.x;  Ks[sk8+1][srow] = ka.y;
    Ks[sk8+2][srow] = ka.z;  Ks[sk8+3][srow] = ka.w;
    Ks[sk8+4][srow] = kb4.x; Ks[sk8+5][srow] = kb4.y;
    Ks[sk8+6][srow] = kb4.z; Ks[sk8+7][srow] = kb4.w;
    Qs[sk8+0][srow] = qa.x;  Qs[sk8+1][srow] = qa.y;
    Qs[sk8+2][srow] = qa.z;  Qs[sk8+3][srow] = qa.w;
    Qs[sk8+4][srow] = qb4.x; Qs[sk8+5][srow] = qb4.y;
    Qs[sk8+6][srow] = qb4.z; Qs[sk8+7][srow] = qb4.w;
    __syncthreads();
    #pragma unroll
    for (int kk = 0; kk < 16; ++kk) {
      float4 a0 = *(float4*)&Ks[kk][ty*8];
      float4 a1 = *(float4*)&Ks[kk][ty*8 + 4];
      float4 b0 = *(float4*)&Qs[kk][tx*8];
      float4 b1 = *(float4*)&Qs[kk][tx*8 + 4];
      float av[8] = {a0.x,a0.y,a0.z,a0.w,a1.x,a1.y,a1.z,a1.w};
      float bv[8] = {b0.x,b0.y,b0.z,b0.w,b1.x,b1.y,b1.z,b1.w};
      #pragma unroll
      for (int d = 0; d < 8; ++d)
        #pragma unroll
        for (int e = 0; e < 8; ++e)
          acc[d][e] = fmaf(av[d], bv[e], acc[d][e]);
    }
  }
  #pragma unroll
  for (int u = 0; u < 8; ++u) {
    int j = j0 + ty*8 + u;
    float kj = k2[b*NSQ + j];
    float* prow = P + (size_t)(b*NSQ + j)*NSQ + i0 + tx*8;
    #pragma unroll
    for (int vv = 0; vv < 8; ++vv) {
      int i = i0 + tx*8 + vv;
      float d2 = kj + q2[b*NSQ + i] - 2.0f * acc[u][vv];
      float e = sqrtf(fmaxf(d2, 1e-12f));
      prow[vv] = 1.0f / (1.0f + log1pf(e));
    }
  }
}

// ---------------------------------------------------------------------------
// Kernel C1b: softmax over j (axis -2) for each (b,i) column, in place.
// R11: 256 blocks x 512 threads, 1 block/CU, 32-load chains.
// ---------------------------------------------------------------------------
__global__ __launch_bounds__(512) void softmax_kernel(float* __restrict__ P) {
  __shared__ float red[16][32];
  const int b = blockIdx.x >> 4;
  const int i0 = (blockIdx.x & 15) * 32;
  const int il = threadIdx.x & 31;
  const int jg = threadIdx.x >> 5;   // 0..15
  float* base = P + (size_t)b*NSQ*NSQ + i0 + il;
  float mx = -1e30f;
  for (int j = jg*32; j < jg*32 + 32; ++j)
    mx = fmaxf(mx, base[(size_t)j*NSQ]);
  red[jg][il] = mx;
  __syncthreads();
  float cm = red[0][il];
  #pragma unroll
  for (int g = 1; g < 16; ++g) cm = fmaxf(cm, red[g][il]);
  __syncthreads();
  float ssum = 0.0f;
  for (int j = jg*32; j < jg*32 + 32; ++j)
    ssum += expf(base[(size_t)j*NSQ] - cm);
  red[jg][il] = ssum;
  __syncthreads();
  float tot = red[0][il];
  #pragma unroll
  for (int g = 1; g < 16; ++g) tot += red[g][il];
  float inv = 1.0f / tot;
  for (int j = jg*32; j < jg*32 + 32; ++j) {
    size_t o = (size_t)j*NSQ;
    base[o] = expf(base[o] - cm) * inv;
  }
}

// ---------------------------------------------------------------------------
// Kernel C2: out[b,c,f] = sum_a P[b,c,a] * vf[b,a,f]   (NN GEMM, K=512)
// R12: 128x128 tile, 256 threads, 8x8 micro, Ps staged K-major (transposed),
// Vs staged row-major (already K-major in f). Bit-identical accumulation.
// ---------------------------------------------------------------------------
__global__ __launch_bounds__(256) void out_gemm_kernel(
    const float* __restrict__ P, const float* __restrict__ vf,
    float* __restrict__ out) {
  __shared__ float Ps[16][132];   // [a][c] transposed
  __shared__ float Vs[16][132];   // [a][f]
  const int b = blockIdx.z;
  const int c0 = blockIdx.y * 128;
  const int f0 = blockIdx.x * 128;
  const int tx = threadIdx.x & 15, ty = threadIdx.x >> 4;  // f-group, c-group
  const int srow = threadIdx.x >> 1;        // P staging row (c) 0..127
  const int sk8  = (threadIdx.x & 1) * 8;   // P staging a-offset 0 or 8
  const int vrow = threadIdx.x >> 4;        // V staging row (a) 0..15
  const int vc8  = (threadIdx.x & 15) * 8;  // V staging f-offset
  float acc[8][8] = {};
  const float* Pb = P + (size_t)b * NSQ * NSQ;
  const float* Vb = vf + (size_t)b * NSQ * NF;
  for (int a0 = 0; a0 < NSQ; a0 += 16) {
    float4 pa = *(const float4*)(Pb + (size_t)(c0 + srow)*NSQ + a0 + sk8);
    float4 pb4 = *(const float4*)(Pb + (size_t)(c0 + srow)*NSQ + a0 + sk8 + 4);
    float4 va = *(const float4*)(Vb + (size_t)(a0 + vrow)*NF + f0 + vc8);
    float4 vb4 = *(const float4*)(Vb + (size_t)(a0 + vrow)*NF + f0 + vc8 + 4);
    __syncthreads();
    Ps[sk8+0][srow] = pa.x;  Ps[sk8+1][srow] = pa.y;
    Ps[sk8+2][srow] = pa.z;  Ps[sk8+3][srow] = pa.w;
    Ps[sk8+4][srow] = pb4.x; Ps[sk8+5][srow] = pb4.y;
    Ps[sk8+6][srow] = pb4.z; Ps[sk8+7][srow] = pb4.w;
    *(float4*)&Vs[vrow][vc8] = va;
    *(float4*)&Vs[vrow][vc8 + 4] = vb4;
    __syncthreads();
    #pragma unroll
    for (int kk = 0; kk < 16; ++kk) {
      float4 a0v = *(float4*)&Ps[kk][ty*8];
      float4 a1v = *(float4*)&Ps[kk][ty*8 + 4];
      float4 b0v = *(float4*)&Vs[kk][tx*8];
      float4 b1v = *(float4*)&Vs[kk][tx*8 + 4];
      float av[8] = {a0v.x,a0v.y,a0v.z,a0v.w,a1v.x,a1v.y,a1v.z,a1v.w};
      float bv[8] = {b0v.x,b0v.y,b0v.z,b0v.w,b1v.x,b1v.y,b1v.z,b1v.w};
      #pragma unroll
      for (int d = 0; d < 8; ++d)
        #pragma unroll
        for (int e = 0; e < 8; ++e)
          acc[d][e] = fmaf(av[d], bv[e], acc[d][e]);
    }
  }
  #pragma unroll
  for (int u = 0; u < 8; ++u) {
    float* orow = out + (size_t)(b*NSQ + c0 + ty*8 + u) * NF + f0 + tx*8;
    float4 o0; o0.x = acc[u][0]; o0.y = acc[u][1]; o0.z = acc[u][2]; o0.w = acc[u][3];
    float4 o1; o1.x = acc[u][4]; o1.y = acc[u][5]; o1.z = acc[u][6]; o1.w = acc[u][7];
    *(float4*)orow = o0;
    *(float4*)(orow + 4) = o1;
  }
}

extern "C" void kernel_launch(void* const* d_in, const int* in_sizes, int n_in,
                              void* d_out, int out_size, void* d_ws, size_t ws_size,
                              hipStream_t stream) {
  const float* x  = (const float*)d_in[0];
  const float* qw = (const float*)d_in[1];
  const float* kw = (const float*)d_in[2];
  const float* vw = (const float*)d_in[3];
  float* ws = (float*)d_ws;
  float* C  = ws;
  float* q  = ws + 3072;
  float* k  = q + (size_t)NMAT * NF;
  float* v  = k + (size_t)NMAT * NF;
  float* q2 = v + (size_t)NMAT * NF;
  float* k2 = q2 + NMAT;
  float* P  = k2 + NMAT;
  float* out = (float*)d_out;

  cayley_kernel<<<dim3(3), dim3(64), 0, stream>>>(qw, kw, vw, C);
  logm_qkv_kernel<<<dim3(NMAT), dim3(128), 0, stream>>>(x, C, q, k, v, q2, k2);
  scores_kernel<<<dim3(4, 4, NB), dim3(256), 0, stream>>>(q, k, q2, k2, P);
  softmax_kernel<<<dim3(NB * 16), dim3(512), 0, stream>>>(P);
  out_gemm_kernel<<<dim3(8, 4, NB), dim3(256), 0, stream>>>(P, v, out);
}

// Round 5
// 1381.605 us; speedup vs baseline: 1.1164x; 1.1164x over previous
//
#include <hip/hip_runtime.h>
#include <math.h>

#define NB 16
#define NSQ 512
#define NMAT (NB*NSQ)   // 8192
#define NF 1024         // 32*32
#define NSWEEP 7        // 6 sweeps FAILS (absmax 0.195); 7 hits the comparison floor.
#define SB 36           // LDS row stride (floats): 144B = multiple of 16 -> b128-aligned rows

// ---------------------------------------------------------------------------
// Native packed-f32 vectors. clang lowers 2-wide float arithmetic to
// v_pk_mul_f32 / v_pk_fma_f32 on gfx950 and keeps values in aligned VGPR
// pairs; shufflevector halves/broadcasts are register aliases / op_sel.
// [R16 LESSON: inline-asm pk ops LOSE the win to operand-repack movs and
//  scheduling constraints - use native vectors, never asm, for this.]
// ---------------------------------------------------------------------------
typedef float f32x2 __attribute__((ext_vector_type(2)));
typedef float f32x4 __attribute__((ext_vector_type(4)));

static __device__ __forceinline__ f32x2 lo2(f32x4 v) { return __builtin_shufflevector(v, v, 0, 1); }
static __device__ __forceinline__ f32x2 hi2(f32x4 v) { return __builtin_shufflevector(v, v, 2, 3); }
static __device__ __forceinline__ f32x4 cat4(f32x2 a, f32x2 b) { return __builtin_shufflevector(a, b, 0, 1, 2, 3); }
static __device__ __forceinline__ f32x2 bclo(f32x2 v) { return __builtin_shufflevector(v, v, 0, 0); }
static __device__ __forceinline__ f32x2 bchi(f32x2 v) { return __builtin_shufflevector(v, v, 1, 1); }

// ---------------------------------------------------------------------------
// Kernel A: Cayley maps. C = (I - X)(I + X)^{-1}, X = W - W^T.
// ---------------------------------------------------------------------------
__global__ __launch_bounds__(64) void cayley_kernel(
    const float* __restrict__ qw, const float* __restrict__ kw,
    const float* __restrict__ vw, float* __restrict__ Cout) {
  __shared__ float M[32][33];
  __shared__ float R[32][33];
  __shared__ float fac[32];
  const float* W = (blockIdx.x == 0) ? qw : ((blockIdx.x == 1) ? kw : vw);
  const int t = threadIdx.x;
  for (int idx = t; idx < 1024; idx += 64) {
    int i = idx >> 5, j = idx & 31;
    float xv = W[i*32+j] - W[j*32+i];
    float d = (i == j) ? 1.0f : 0.0f;
    M[i][j] = d - xv;
    R[i][j] = d + xv;
  }
  __syncthreads();
  for (int k = 0; k < 32; ++k) {
    float inv = 1.0f / M[k][k];
    __syncthreads();
    if (t < 32) M[k][t] *= inv; else R[k][t-32] *= inv;
    __syncthreads();
    if (t < 32) fac[t] = M[t][k];
    __syncthreads();
    if (t < 32) {
      float mk = M[k][t];
      for (int i = 0; i < 32; ++i) {
        if (i == k) continue;
        M[i][t] -= fac[i] * mk;
      }
    } else {
      int tc = t - 32;
      float rk = R[k][tc];
      for (int i = 0; i < 32; ++i) {
        if (i == k) continue;
        R[i][tc] -= fac[i] * rk;
      }
    }
    __syncthreads();
  }
  // R = C^T ; store C row-major: C[p][q] = R[q][p]
  for (int idx = t; idx < 1024; idx += 64) {
    int p = idx >> 5, q = idx & 31;
    Cout[blockIdx.x * 1024 + idx] = R[q][p];
  }
}

// ---------------------------------------------------------------------------
// Kernel B: per-matrix sym eigendecomposition (parallel Jacobi, XOR pairing),
// then S = V log(w) V^T (zero diag), then q/k/v = offdiag(C S C^T) + norms.
// R17: EXACT R10 structure (3 LDS buffers, 128 thr, register index math,
// LDS-staged C epilogue, same barriers) + NATIVE-vector packed-f32 rotations:
// Vt & r==1 phase-A 16->8 pk; 2x2 phase 16->8 pk per u-block (column-wise
// formulation: row-rot = within-vector broadcast form, col-rot elementwise).
// [R16: asm pk LOSES to repack movs - native vectors only.]
// [R13: 1-wave/64-thr LOSES - VGPR 116 halves resident waves.]
// [R14: LDS pair-offset tables LOSE - conflicts 1.3e8->4.4e8, +515us.]
// [R15: global-C epilogue LOSES - VGPR 52->84, +140us. Keep buf2.]
// [R8/R9: 2-buffer LDS epilogues cost registers and LOSE.]
// [R4/R5/R6: fused/two-phase r<=3 variants FAILED - do not revisit.]
// ---------------------------------------------------------------------------
__global__ __launch_bounds__(128) void logm_qkv_kernel(
    const float* __restrict__ x, const float* __restrict__ Cm,
    float* __restrict__ qo, float* __restrict__ ko, float* __restrict__ vo,
    float* __restrict__ q2, float* __restrict__ k2) {
  __shared__ __align__(16) float buf0[32*SB];   // A -> Vrow -> (per w) C
  __shared__ __align__(16) float buf1[32*SB];   // Vt -> T (=offdiag S)
  __shared__ __align__(16) float buf2[32*SB];   // U
  __shared__ __align__(16) float2 cs[16];
  __shared__ __align__(16) float lw[32];
  __shared__ float wsum[2];
  const int t = threadIdx.x;
  const int m = blockIdx.x;
  const float* xm = x + (size_t)m * NF;

  // init A = x (stride SB, b128) and Vt = I : 256 float4 tasks, 2/thread
  #pragma unroll
  for (int s = 0; s < 2; ++s) {
    int fi = t + 128*s;              // float4 index 0..255
    int i = fi >> 3, j4 = (fi & 7) << 2;
    float4 xv = *(const float4*)&xm[(size_t)fi*4];
    *(float4*)&buf0[i*SB + j4] = xv;
    float4 iv;
    iv.x = (i == j4+0) ? 1.0f : 0.0f;
    iv.y = (i == j4+1) ? 1.0f : 0.0f;
    iv.z = (i == j4+2) ? 1.0f : 0.0f;
    iv.w = (i == j4+3) ? 1.0f : 0.0f;
    *(float4*)&buf1[i*SB + j4] = iv;
  }
  __syncthreads();

  const int abase = t >> 4;    // row-pair group 0..7
  const int bI = t & 15;       // col-pair index
  const int pi = abase & 1;    // role-swap parity

  for (int sw = 0; sw < NSWEEP; ++sw) {
    for (int r = 1; r < 32; ++r) {
      const int h = 31 - __builtin_clz((unsigned)r);
      const int lowmask = (1 << h) - 1;
      // phase 1: rotation angles for the 16 disjoint pairs {p, p^r}
      if (t < 16) {
        int p = ((t >> h) << (h+1)) | (t & lowmask);
        int q = p ^ r;
        float apq = buf0[p*SB+q];
        float c = 1.0f, s = 0.0f;
        if (fabsf(apq) > 1e-36f) {
          float app = buf0[p*SB+p];
          float aqq = buf0[q*SB+q];
          float tau = (aqq - app) / (2.0f * apq);
          float tt = 1.0f / (fabsf(tau) + sqrtf(1.0f + tau*tau));
          tt = (tau < 0.0f) ? -tt : tt;
          c = 1.0f / sqrtf(1.0f + tt*tt);
          s = tt * c;
        }
        cs[t] = make_float2(c, s);
      }
      __syncthreads();
      if (r == 1) {
        // --- phase A: row rotations B = J^T A (b128, packed); pairs
        //     (2k,2k+1); 128 tasks (16 pairs x 8 chunks), 1 per thread ---
        {
          int pr = t >> 3;                 // pair 0..15
          int ch = (t & 7) << 2;           // column chunk
          int p = pr << 1;                 // h=0 -> p = 2*pr
          int q = p | 1;
          f32x2 C2 = *(f32x2*)&cs[pr];     // (c,s)
          f32x2 cc = bclo(C2), ss = bchi(C2);
          f32x4 ap = *(f32x4*)&buf0[p*SB + ch];
          f32x4 aq = *(f32x4*)&buf0[q*SB + ch];
          f32x2 ap0 = lo2(ap), ap1 = hi2(ap);
          f32x2 aq0 = lo2(aq), aq1 = hi2(aq);
          f32x2 np0 = ap0*cc - aq0*ss;
          f32x2 np1 = ap1*cc - aq1*ss;
          f32x2 nq0 = ap0*ss + aq0*cc;
          f32x2 nq1 = ap1*ss + aq1*cc;
          *(f32x4*)&buf0[p*SB + ch] = cat4(np0, np1);
          *(f32x4*)&buf0[q*SB + ch] = cat4(nq0, nq1);
        }
        __syncthreads();   // r is loop-uniform -> all threads reach this
        // --- phase B: col rotations A' = B J, in-register per row-chunk;
        //     local col pairs (0,1) w/ cs[2c] and (2,3) w/ cs[2c+1];
        //     256 tasks, 2 per thread ---
        #pragma unroll
        for (int s4 = 0; s4 < 2; ++s4) {
          int tsk = t + 128*s4;            // 0..255
          int i = tsk >> 3;                // row 0..31
          int cch = tsk & 7;               // chunk 0..7 (cols 4c..4c+3)
          float2 cA = cs[2*cch];
          float2 cB = cs[2*cch+1];
          float4 y = *(float4*)&buf0[i*SB + 4*cch];
          float4 z;
          z.x = cA.x*y.x - cA.y*y.y;  z.y = fmaf(cA.y, y.x, cA.x*y.y);
          z.z = cB.x*y.z - cB.y*y.w;  z.w = fmaf(cB.y, y.z, cB.x*y.w);
          *(float4*)&buf0[i*SB + 4*cch] = z;
        }
      } else {
        // blocked 2x2 update, pi-swapped, packed column-wise; 256 blocks,
        // 2 per thread. Xp=(x11,x21) col pb, Xq=(x12,x22) col qb:
        // row-rot within-vector (broadcast form), col-rot elementwise.
        int pb = ((bI >> h) << (h+1)) | (bI & lowmask);
        int qb = pb ^ r;
        if (pi) { int tmp = pb; pb = qb; qb = tmp; }
        const float2 cb2 = cs[bI];
        const float cbb = cb2.x;
        const float sbb = pi ? -cb2.y : cb2.y;
        f32x2 CBc; CBc.x = cbb; CBc.y = cbb;
        f32x2 CBs; CBs.x = sbb; CBs.y = sbb;
        #pragma unroll
        for (int u = 0; u < 2; ++u) {
          int a = abase + 8*u;
          int pa = ((a >> h) << (h+1)) | (a & lowmask);
          int qa = pa ^ r;
          if (pi) { int tmp = pa; pa = qa; qa = tmp; }
          float2 ca2 = cs[a];
          float caa = ca2.x;
          float saa = pi ? -ca2.y : ca2.y;
          f32x2 CA2;  CA2.x  = caa;  CA2.y  = saa;
          f32x2 CA2n; CA2n.x = -saa; CA2n.y = caa;
          float* rp = buf0 + pa*SB;
          float* rq = buf0 + qa*SB;
          f32x2 Xp; Xp.x = rp[pb]; Xp.y = rq[pb];   // (x11, x21)
          f32x2 Xq; Xq.x = rp[qb]; Xq.y = rq[qb];   // (x12, x22)
          f32x2 Yp = CA2*bclo(Xp) + CA2n*bchi(Xp);  // (y11, y21)
          f32x2 Yq = CA2*bclo(Xq) + CA2n*bchi(Xq);  // (y12, y22)
          f32x2 Zp = Yp*CBc - Yq*CBs;               // new col pb
          f32x2 Zq = Yp*CBs + Yq*CBc;               // new col qb
          rp[pb] = Zp.x; rq[pb] = Zp.y;
          rp[qb] = Zq.x; rq[qb] = Zq.y;
        }
      }
      // V^T row rotations (Vt = J^T Vt, packed), 128 float4 tasks, 1/thread
      {
        int pr = t >> 3;                 // pair 0..15
        int ch = (t & 7) << 2;           // column chunk
        int p = ((pr >> h) << (h+1)) | (pr & lowmask);
        int q = p ^ r;
        f32x2 C2 = *(f32x2*)&cs[pr];     // (c,s)
        f32x2 cc = bclo(C2), ss = bchi(C2);
        f32x4 vp = *(f32x4*)&buf1[p*SB + ch];
        f32x4 vq = *(f32x4*)&buf1[q*SB + ch];
        f32x2 vp0 = lo2(vp), vp1 = hi2(vp);
        f32x2 vq0 = lo2(vq), vq1 = hi2(vq);
        f32x2 np0 = vp0*cc - vq0*ss;
        f32x2 np1 = vp1*cc - vq1*ss;
        f32x2 nq0 = vp0*ss + vq0*cc;
        f32x2 nq1 = vp1*ss + vq1*cc;
        *(f32x4*)&buf1[p*SB + ch] = cat4(np0, np1);
        *(f32x4*)&buf1[q*SB + ch] = cat4(nq0, nq1);
      }
      __syncthreads();
    }
  }

  if (t < 32) lw[t] = logf(fmaxf(buf0[t*SB+t], 1e-30f));
  __syncthreads();
  // transpose Vt(buf1) -> Vrow(buf0): 1024 scalars, 8 per thread
  #pragma unroll
  for (int s = 0; s < 8; ++s) {
    int idx = t + 128*s;
    int i = idx >> 5, k = idx & 31;
    buf0[i*SB + k] = buf1[k*SB + i];
  }
  __syncthreads();

  // tile partition: 128 threads own 4x2 output tiles (8 row-groups x 16 col-groups)
  const int rg = t >> 4, cg = t & 15;
  const int i0 = rg*4, j0 = cg*2;
  // T = offdiag(S), S[i][j] = sum_k (Vrow[i][k]*lw[k]) * Vrow[j][k]  -> buf1
  {
    float acc[4][2] = {};
    #pragma unroll
    for (int k4 = 0; k4 < 32; k4 += 4) {
      float4 lv = *(float4*)&lw[k4];
      float4 av[4], bv[2];
      #pragma unroll
      for (int d = 0; d < 4; ++d) {
        float4 a4 = *(float4*)&buf0[(i0+d)*SB + k4];
        av[d].x = a4.x*lv.x; av[d].y = a4.y*lv.y; av[d].z = a4.z*lv.z; av[d].w = a4.w*lv.w;
      }
      #pragma unroll
      for (int e = 0; e < 2; ++e)
        bv[e] = *(float4*)&buf0[(j0+e)*SB + k4];
      #pragma unroll
      for (int d = 0; d < 4; ++d)
        #pragma unroll
        for (int e = 0; e < 2; ++e) {
          acc[d][e] = fmaf(av[d].x, bv[e].x, acc[d][e]);
          acc[d][e] = fmaf(av[d].y, bv[e].y, acc[d][e]);
          acc[d][e] = fmaf(av[d].z, bv[e].z, acc[d][e]);
          acc[d][e] = fmaf(av[d].w, bv[e].w, acc[d][e]);
        }
    }
    #pragma unroll
    for (int d = 0; d < 4; ++d) {
      #pragma unroll
      for (int e = 0; e < 2; ++e)
        if (i0+d == j0+e) acc[d][e] = 0.0f;
      float2 z; z.x = acc[d][0]; z.y = acc[d][1];
      *(float2*)&buf1[(i0+d)*SB + j0] = z;
    }
  }
  __syncthreads();

  for (int w = 0; w < 3; ++w) {
    const float* Cw = Cm + w*1024;
    // load C -> buf0 (over dead Vrow), 256 float4, 2 per thread
    #pragma unroll
    for (int s = 0; s < 2; ++s) {
      int fi = t + 128*s;
      int i = fi >> 3, c4 = (fi & 7) << 2;
      *(float4*)&buf0[i*SB + c4] = *(const float4*)&Cw[fi*4];
    }
    __syncthreads();
    // U = C * T (T symmetric): U[i][j] = sum_k C[i][k] * T[j][k] -> buf2
    {
      float acc[4][2] = {};
      #pragma unroll
      for (int k4 = 0; k4 < 32; k4 += 4) {
        float4 av[4], bv[2];
        #pragma unroll
        for (int d = 0; d < 4; ++d)
          av[d] = *(float4*)&buf0[(i0+d)*SB + k4];
        #pragma unroll
        for (int e = 0; e < 2; ++e)
          bv[e] = *(float4*)&buf1[(j0+e)*SB + k4];
        #pragma unroll
        for (int d = 0; d < 4; ++d)
          #pragma unroll
          for (int e = 0; e < 2; ++e) {
            acc[d][e] = fmaf(av[d].x, bv[e].x, acc[d][e]);
            acc[d][e] = fmaf(av[d].y, bv[e].y, acc[d][e]);
            acc[d][e] = fmaf(av[d].z, bv[e].z, acc[d][e]);
            acc[d][e] = fmaf(av[d].w, bv[e].w, acc[d][e]);
          }
      }
      #pragma unroll
      for (int d = 0; d < 4; ++d) {
        float2 z; z.x = acc[d][0]; z.y = acc[d][1];
        *(float2*)&buf2[(i0+d)*SB + j0] = z;
      }
    }
    __syncthreads();
    // Z = U * C^T: Z[i][j] = sum_k U[i][k] * C[j][k]; offdiag -> global
    {
      float acc[4][2] = {};
      #pragma unroll
      for (int k4 = 0; k4 < 32; k4 += 4) {
        float4 av[4], bv[2];
        #pragma unroll
        for (int d = 0; d < 4; ++d)
          av[d] = *(float4*)&buf2[(i0+d)*SB + k4];
        #pragma unroll
        for (int e = 0; e < 2; ++e)
          bv[e] = *(float4*)&buf0[(j0+e)*SB + k4];
        #pragma unroll
        for (int d = 0; d < 4; ++d)
          #pragma unroll
          for (int e = 0; e < 2; ++e) {
            acc[d][e] = fmaf(av[d].x, bv[e].x, acc[d][e]);
            acc[d][e] = fmaf(av[d].y, bv[e].y, acc[d][e]);
            acc[d][e] = fmaf(av[d].z, bv[e].z, acc[d][e]);
            acc[d][e] = fmaf(av[d].w, bv[e].w, acc[d][e]);
          }
      }
      float ss = 0.0f;
      float* outp = (w == 0) ? qo : ((w == 1) ? ko : vo);
      #pragma unroll
      for (int d = 0; d < 4; ++d) {
        #pragma unroll
        for (int e = 0; e < 2; ++e) {
          if (i0+d == j0+e) acc[d][e] = 0.0f;
          ss = fmaf(acc[d][e], acc[d][e], ss);
        }
        float2 z; z.x = acc[d][0]; z.y = acc[d][1];
        *(float2*)&outp[(size_t)m*NF + (i0+d)*32 + j0] = z;
      }
      if (w < 2) {
        #pragma unroll
        for (int off = 32; off > 0; off >>= 1)
          ss += __shfl_down(ss, off);
        if ((t & 63) == 0) wsum[t >> 6] = ss;
      }
      __syncthreads();   // wsum visible; Z reads of buf0/buf2 done
      if (w < 2 && t == 0)
        ((w == 0) ? q2 : k2)[m] = wsum[0] + wsum[1];
    }
  }
}

// ---------------------------------------------------------------------------
// Kernel C1: G[b,j,i] = <kf[b,j], qf[b,i]> (K=1024), fused scores epilogue.
// R12: 128x128 tile, 256 threads, 8x8 micro-tile, K-major (transposed)
// staging -> inner loop is 4 broadcast ds_read_b128 vs 64 fma (compute-bound;
// old 64-tile/4x4 was 16 scalar ds_read per 32 fma -> LDS-bound, ~40% peak).
// Same K-accumulation order per element -> bit-identical output.
// ---------------------------------------------------------------------------
__global__ __launch_bounds__(256) void scores_kernel(
    const float* __restrict__ qf, const float* __restrict__ kf,
    const float* __restrict__ q2, const float* __restrict__ k2,
    float* __restrict__ P) {
  __shared__ float Ks[16][132];   // [k][j] transposed
  __shared__ float Qs[16][132];   // [k][i] transposed
  const int b = blockIdx.z;
  const int j0 = blockIdx.y * 128;
  const int i0 = blockIdx.x * 128;
  const int tx = threadIdx.x & 15, ty = threadIdx.x >> 4;  // i-group, j-group
  const int srow = threadIdx.x >> 1;        // staging row 0..127
  const int sk8  = (threadIdx.x & 1) * 8;   // staging k-offset 0 or 8
  float acc[8][8] = {};
  const float* kb = kf + (size_t)(b*NSQ + j0) * NF;
  const float* qb = qf + (size_t)(b*NSQ + i0) * NF;
  for (int f0 = 0; f0 < NF; f0 += 16) {
    float4 ka = *(const float4*)(kb + (size_t)srow*NF + f0 + sk8);
    float4 kb4 = *(const float4*)(kb + (size_t)srow*NF + f0 + sk8 + 4);
    float4 qa = *(const float4*)(qb + (size_t)srow*NF + f0 + sk8);
    float4 qb4 = *(const float4*)(qb + (size_t)srow*NF + f0 + sk8 + 4);
    __syncthreads();   // prev iteration's reads done before overwrite
    Ks[sk8+0][srow] = ka.x;  Ks[sk8+1][srow] = ka.y;
    Ks[sk8+2][srow] = ka.z;  Ks[sk8+3][srow] = ka.w;
    Ks[sk8+4][srow] = kb4.x; Ks[sk8+5][srow] = kb4.y;
    Ks[sk8+6][srow] = kb4.z; Ks[sk8+7][srow] = kb4.w;
    Qs[sk8+0][srow] = qa.x;  Qs[sk8+1][srow] = qa.y;
    Qs[sk8+2][srow] = qa.z;  Qs[sk8+3][srow] = qa.w;
    Qs[sk8+4][srow] = qb4.x; Qs[sk8+5][srow] = qb4.y;
    Qs[sk8+6][srow] = qb4.z; Qs[sk8+7][srow] = qb4.w;
    __syncthreads();
    #pragma unroll
    for (int kk = 0; kk < 16; ++kk) {
      float4 a0 = *(float4*)&Ks[kk][ty*8];
      float4 a1 = *(float4*)&Ks[kk][ty*8 + 4];
      float4 b0 = *(float4*)&Qs[kk][tx*8];
      float4 b1 = *(float4*)&Qs[kk][tx*8 + 4];
      float av[8] = {a0.x,a0.y,a0.z,a0.w,a1.x,a1.y,a1.z,a1.w};
      float bv[8] = {b0.x,b0.y,b0.z,b0.w,b1.x,b1.y,b1.z,b1.w};
      #pragma unroll
      for (int d = 0; d < 8; ++d)
        #pragma unroll
        for (int e = 0; e < 8; ++e)
          acc[d][e] = fmaf(av[d], bv[e], acc[d][e]);
    }
  }
  #pragma unroll
  for (int u = 0; u < 8; ++u) {
    int j = j0 + ty*8 + u;
    float kj = k2[b*NSQ + j];
    float* prow = P + (size_t)(b*NSQ + j)*NSQ + i0 + tx*8;
    #pragma unroll
    for (int vv = 0; vv < 8; ++vv) {
      int i = i0 + tx*8 + vv;
      float d2 = kj + q2[b*NSQ + i] - 2.0f * acc[u][vv];
      float e = sqrtf(fmaxf(d2, 1e-12f));
      prow[vv] = 1.0f / (1.0f + log1pf(e));
    }
  }
}

// ---------------------------------------------------------------------------
// Kernel C1b: softmax over j (axis -2) for each (b,i) column, in place.
// R11: 256 blocks x 512 threads, 1 block/CU, 32-load chains.
// ---------------------------------------------------------------------------
__global__ __launch_bounds__(512) void softmax_kernel(float* __restrict__ P) {
  __shared__ float red[16][32];
  const int b = blockIdx.x >> 4;
  const int i0 = (blockIdx.x & 15) * 32;
  const int il = threadIdx.x & 31;
  const int jg = threadIdx.x >> 5;   // 0..15
  float* base = P + (size_t)b*NSQ*NSQ + i0 + il;
  float mx = -1e30f;
  for (int j = jg*32; j < jg*32 + 32; ++j)
    mx = fmaxf(mx, base[(size_t)j*NSQ]);
  red[jg][il] = mx;
  __syncthreads();
  float cm = red[0][il];
  #pragma unroll
  for (int g = 1; g < 16; ++g) cm = fmaxf(cm, red[g][il]);
  __syncthreads();
  float ssum = 0.0f;
  for (int j = jg*32; j < jg*32 + 32; ++j)
    ssum += expf(base[(size_t)j*NSQ] - cm);
  red[jg][il] = ssum;
  __syncthreads();
  float tot = red[0][il];
  #pragma unroll
  for (int g = 1; g < 16; ++g) tot += red[g][il];
  float inv = 1.0f / tot;
  for (int j = jg*32; j < jg*32 + 32; ++j) {
    size_t o = (size_t)j*NSQ;
    base[o] = expf(base[o] - cm) * inv;
  }
}

// ---------------------------------------------------------------------------
// Kernel C2: out[b,c,f] = sum_a P[b,c,a] * vf[b,a,f]   (NN GEMM, K=512)
// R12: 128x128 tile, 256 threads, 8x8 micro, Ps staged K-major (transposed),
// Vs staged row-major (already K-major in f). Bit-identical accumulation.
// ---------------------------------------------------------------------------
__global__ __launch_bounds__(256) void out_gemm_kernel(
    const float* __restrict__ P, const float* __restrict__ vf,
    float* __restrict__ out) {
  __shared__ float Ps[16][132];   // [a][c] transposed
  __shared__ float Vs[16][132];   // [a][f]
  const int b = blockIdx.z;
  const int c0 = blockIdx.y * 128;
  const int f0 = blockIdx.x * 128;
  const int tx = threadIdx.x & 15, ty = threadIdx.x >> 4;  // f-group, c-group
  const int srow = threadIdx.x >> 1;        // P staging row (c) 0..127
  const int sk8  = (threadIdx.x & 1) * 8;   // P staging a-offset 0 or 8
  const int vrow = threadIdx.x >> 4;        // V staging row (a) 0..15
  const int vc8  = (threadIdx.x & 15) * 8;  // V staging f-offset
  float acc[8][8] = {};
  const float* Pb = P + (size_t)b * NSQ * NSQ;
  const float* Vb = vf + (size_t)b * NSQ * NF;
  for (int a0 = 0; a0 < NSQ; a0 += 16) {
    float4 pa = *(const float4*)(Pb + (size_t)(c0 + srow)*NSQ + a0 + sk8);
    float4 pb4 = *(const float4*)(Pb + (size_t)(c0 + srow)*NSQ + a0 + sk8 + 4);
    float4 va = *(const float4*)(Vb + (size_t)(a0 + vrow)*NF + f0 + vc8);
    float4 vb4 = *(const float4*)(Vb + (size_t)(a0 + vrow)*NF + f0 + vc8 + 4);
    __syncthreads();
    Ps[sk8+0][srow] = pa.x;  Ps[sk8+1][srow] = pa.y;
    Ps[sk8+2][srow] = pa.z;  Ps[sk8+3][srow] = pa.w;
    Ps[sk8+4][srow] = pb4.x; Ps[sk8+5][srow] = pb4.y;
    Ps[sk8+6][srow] = pb4.z; Ps[sk8+7][srow] = pb4.w;
    *(float4*)&Vs[vrow][vc8] = va;
    *(float4*)&Vs[vrow][vc8 + 4] = vb4;
    __syncthreads();
    #pragma unroll
    for (int kk = 0; kk < 16; ++kk) {
      float4 a0v = *(float4*)&Ps[kk][ty*8];
      float4 a1v = *(float4*)&Ps[kk][ty*8 + 4];
      float4 b0v = *(float4*)&Vs[kk][tx*8];
      float4 b1v = *(float4*)&Vs[kk][tx*8 + 4];
      float av[8] = {a0v.x,a0v.y,a0v.z,a0v.w,a1v.x,a1v.y,a1v.z,a1v.w};
      float bv[8] = {b0v.x,b0v.y,b0v.z,b0v.w,b1v.x,b1v.y,b1v.z,b1v.w};
      #pragma unroll
      for (int d = 0; d < 8; ++d)
        #pragma unroll
        for (int e = 0; e < 8; ++e)
          acc[d][e] = fmaf(av[d], bv[e], acc[d][e]);
    }
  }
  #pragma unroll
  for (int u = 0; u < 8; ++u) {
    float* orow = out + (size_t)(b*NSQ + c0 + ty*8 + u) * NF + f0 + tx*8;
    float4 o0; o0.x = acc[u][0]; o0.y = acc[u][1]; o0.z = acc[u][2]; o0.w = acc[u][3];
    float4 o1; o1.x = acc[u][4]; o1.y = acc[u][5]; o1.z = acc[u][6]; o1.w = acc[u][7];
    *(float4*)orow = o0;
    *(float4*)(orow + 4) = o1;
  }
}

extern "C" void kernel_launch(void* const* d_in, const int* in_sizes, int n_in,
                              void* d_out, int out_size, void* d_ws, size_t ws_size,
                              hipStream_t stream) {
  const float* x  = (const float*)d_in[0];
  const float* qw = (const float*)d_in[1];
  const float* kw = (const float*)d_in[2];
  const float* vw = (const float*)d_in[3];
  float* ws = (float*)d_ws;
  float* C  = ws;
  float* q  = ws + 3072;
  float* k  = q + (size_t)NMAT * NF;
  float* v  = k + (size_t)NMAT * NF;
  float* q2 = v + (size_t)NMAT * NF;
  float* k2 = q2 + NMAT;
  float* P  = k2 + NMAT;
  float* out = (float*)d_out;

  cayley_kernel<<<dim3(3), dim3(64), 0, stream>>>(qw, kw, vw, C);
  logm_qkv_kernel<<<dim3(NMAT), dim3(128), 0, stream>>>(x, C, q, k, v, q2, k2);
  scores_kernel<<<dim3(4, 4, NB), dim3(256), 0, stream>>>(q, k, q2, k2, P);
  softmax_kernel<<<dim3(NB * 16), dim3(512), 0, stream>>>(P);
  out_gemm_kernel<<<dim3(8, 4, NB), dim3(256), 0, stream>>>(P, v, out);
}